// Round 1
// baseline (370.076 us; speedup 1.0000x reference)
//
#include <hip/hip_runtime.h>

#define N_NODES 50000
#define N_EDGES 600000
#define DD 128

typedef __attribute__((ext_vector_type(8))) short short8;
typedef __attribute__((ext_vector_type(4))) float f32x4;

// fp32 -> bf16 round-to-nearest-even (bit trick; cheap, no header type issues)
__device__ __forceinline__ short f2bf(float f) {
    union { float f; unsigned u; } v; v.f = f;
    unsigned r = v.u + 0x7fffu + ((v.u >> 16) & 1u);
    return (short)(r >> 16);
}

// ---------------------------------------------------------------------------
// Kernel 1: obj_lin[50000][128] = obj_vecs @ W_obj^T + b_obj   (bf16 MFMA)
// 16-row tiles, 4 waves/block, W in LDS as [n][k] bf16 with +8 pad.
// ---------------------------------------------------------------------------
__global__ __launch_bounds__(256) void k_objlin(const float* __restrict__ X,
                                                const float* __restrict__ W,
                                                const float* __restrict__ bias,
                                                float* __restrict__ Y) {
    __shared__ __align__(16) short Wl[128 * 136];
    for (int i = threadIdx.x; i < 128 * 128; i += 256) {
        int n = i >> 7, k = i & 127;
        Wl[n * 136 + k] = f2bf(W[i]);
    }
    __syncthreads();

    const int wave = threadIdx.x >> 6;
    const int lane = threadIdx.x & 63;
    const int g = lane >> 4, ln = lane & 15;
    const int t = blockIdx.x * 4 + wave;          // 16-row tile index
    if (t >= (N_NODES / 16)) return;              // 3125 tiles exactly

    const int row = t * 16 + ln;
    const float* xr = X + (size_t)row * DD;

    short8 a[4];
#pragma unroll
    for (int ks = 0; ks < 4; ++ks) {
        const float* p = xr + ks * 32 + g * 8;
        float4 t0 = *(const float4*)p;
        float4 t1 = *(const float4*)(p + 4);
        short8 v;
        v[0] = f2bf(t0.x); v[1] = f2bf(t0.y); v[2] = f2bf(t0.z); v[3] = f2bf(t0.w);
        v[4] = f2bf(t1.x); v[5] = f2bf(t1.y); v[6] = f2bf(t1.z); v[7] = f2bf(t1.w);
        a[ks] = v;
    }

#pragma unroll
    for (int nt = 0; nt < 8; ++nt) {
        f32x4 acc = {0.f, 0.f, 0.f, 0.f};
#pragma unroll
        for (int ks = 0; ks < 4; ++ks) {
            short8 b = *(const short8*)&Wl[(nt * 16 + ln) * 136 + ks * 32 + g * 8];
            acc = __builtin_amdgcn_mfma_f32_16x16x32_bf16(a[ks], b, acc, 0, 0, 0);
        }
        const int col = nt * 16 + ln;
        const float bb = bias[col];
#pragma unroll
        for (int r = 0; r < 4; ++r) {
            const int orow = t * 16 + g * 4 + r;
            Y[(size_t)orow * DD + col] = acc[r] + bb;
        }
    }
}

// ---------------------------------------------------------------------------
// Kernel 2: fused rel GEMM + gather(obj_lin[src],obj_lin[dst]) + ReLU +
//           atomicAdd scatter into out (segment sum).
// ---------------------------------------------------------------------------
__global__ __launch_bounds__(256) void k_edges(const float* __restrict__ RV,
                                               const int* __restrict__ EI,
                                               const float* __restrict__ W,
                                               const float* __restrict__ bias,
                                               const float* __restrict__ OL,
                                               float* __restrict__ out) {
    __shared__ __align__(16) short Wl[128 * 136];
    for (int i = threadIdx.x; i < 128 * 128; i += 256) {
        int n = i >> 7, k = i & 127;
        Wl[n * 136 + k] = f2bf(W[i]);
    }
    __syncthreads();

    const int wave = threadIdx.x >> 6;
    const int lane = threadIdx.x & 63;
    const int g = lane >> 4, ln = lane & 15;

    float brel[8];
#pragma unroll
    for (int nt = 0; nt < 8; ++nt) brel[nt] = bias[nt * 16 + ln];

    const int NGROUPS = N_EDGES / 64;             // 9375 groups of 4 tiles
    for (int gi = blockIdx.x; gi < NGROUPS; gi += gridDim.x) {
        const int t = gi * 4 + wave;              // 16-edge tile
        const int e0 = t * 16;
        const float* xr = RV + (size_t)(e0 + ln) * DD;

        short8 a[4];
#pragma unroll
        for (int ks = 0; ks < 4; ++ks) {
            const float* p = xr + ks * 32 + g * 8;
            float4 t0 = *(const float4*)p;
            float4 t1 = *(const float4*)(p + 4);
            short8 v;
            v[0] = f2bf(t0.x); v[1] = f2bf(t0.y); v[2] = f2bf(t0.z); v[3] = f2bf(t0.w);
            v[4] = f2bf(t1.x); v[5] = f2bf(t1.y); v[6] = f2bf(t1.z); v[7] = f2bf(t1.w);
            a[ks] = v;
        }

        f32x4 acc[8];
#pragma unroll
        for (int nt = 0; nt < 8; ++nt) {
            acc[nt] = (f32x4){0.f, 0.f, 0.f, 0.f};
#pragma unroll
            for (int ks = 0; ks < 4; ++ks) {
                short8 b = *(const short8*)&Wl[(nt * 16 + ln) * 136 + ks * 32 + g * 8];
                acc[nt] = __builtin_amdgcn_mfma_f32_16x16x32_bf16(a[ks], b, acc[nt], 0, 0, 0);
            }
        }

        // Epilogue: lane (g,ln) owns rows g*4+r, col = nt*16+ln.
#pragma unroll
        for (int r = 0; r < 4; ++r) {
            const int e = e0 + g * 4 + r;
            const int2 sd = *(const int2*)(EI + 2 * e);
            const int src = sd.x, dst = sd.y;
            const float* ps = OL + (size_t)src * DD + ln;
            const float* pd = OL + (size_t)dst * DD + ln;
            float* po = out + (size_t)dst * DD + ln;
#pragma unroll
            for (int nt = 0; nt < 8; ++nt) {
                float v = acc[nt][r] + brel[nt] + ps[nt * 16] + pd[nt * 16];
                v = fmaxf(v, 0.f);
                atomicAdd(po + nt * 16, v);
            }
        }
    }
}

// ---------------------------------------------------------------------------
// Zero + final ReLU passes
// ---------------------------------------------------------------------------
__global__ __launch_bounds__(256) void k_zero(float4* __restrict__ p, int n4) {
    int i = blockIdx.x * 256 + threadIdx.x;
    if (i < n4) p[i] = (float4){0.f, 0.f, 0.f, 0.f};
}

__global__ __launch_bounds__(256) void k_relu(float4* __restrict__ p, int n4) {
    int i = blockIdx.x * 256 + threadIdx.x;
    if (i < n4) {
        float4 v = p[i];
        v.x = fmaxf(v.x, 0.f); v.y = fmaxf(v.y, 0.f);
        v.z = fmaxf(v.z, 0.f); v.w = fmaxf(v.w, 0.f);
        p[i] = v;
    }
}

extern "C" void kernel_launch(void* const* d_in, const int* in_sizes, int n_in,
                              void* d_out, int out_size, void* d_ws, size_t ws_size,
                              hipStream_t stream) {
    const float* obj = (const float*)d_in[0];
    const float* rel = (const float*)d_in[1];
    const int*   ei  = (const int*)d_in[2];
    const float* Wo  = (const float*)d_in[3];
    const float* bo  = (const float*)d_in[4];
    const float* Wr  = (const float*)d_in[5];
    const float* br  = (const float*)d_in[6];
    float* out = (float*)d_out;
    float* objlin = (float*)d_ws;                 // 50000*128 fp32 = 25.6 MB

    const int n4 = N_NODES * DD / 4;              // 1,600,000 float4
    k_zero<<<(n4 + 255) / 256, 256, 0, stream>>>((float4*)out, n4);
    k_objlin<<<(N_NODES / 16 + 3) / 4, 256, 0, stream>>>(obj, Wo, bo, objlin);
    k_edges<<<2048, 256, 0, stream>>>(rel, ei, Wr, br, objlin, out);
    k_relu<<<(n4 + 255) / 256, 256, 0, stream>>>((float4*)out, n4);
}

// Round 2
// 334.433 us; speedup vs baseline: 1.1066x; 1.1066x over previous
//
#include <hip/hip_runtime.h>

#define N_NODES 50000
#define N_EDGES 600000
#define DD 128

typedef __attribute__((ext_vector_type(8))) short short8;
typedef __attribute__((ext_vector_type(4))) float f32x4;

__device__ __forceinline__ short f2bf(float f) {
    union { float f; unsigned u; } v; v.f = f;
    unsigned r = v.u + 0x7fffu + ((v.u >> 16) & 1u);
    return (short)(r >> 16);
}
__device__ __forceinline__ float bf2f(short s) {
    union { float f; unsigned u; } v; v.u = ((unsigned)(unsigned short)s) << 16;
    return v.f;
}

// ---------------------------------------------------------------------------
// obj_lin[50000][128] = obj_vecs @ W_obj^T + b_obj   -> stored as bf16
// ---------------------------------------------------------------------------
__global__ __launch_bounds__(256) void k_objlin(const float* __restrict__ X,
                                                const float* __restrict__ W,
                                                const float* __restrict__ bias,
                                                short* __restrict__ Y) {
    __shared__ __align__(16) short Wl[128 * 136];
    for (int i = threadIdx.x; i < 128 * 128; i += 256) {
        int n = i >> 7, k = i & 127;
        Wl[n * 136 + k] = f2bf(W[i]);
    }
    __syncthreads();

    const int wave = threadIdx.x >> 6;
    const int lane = threadIdx.x & 63;
    const int g = lane >> 4, ln = lane & 15;
    const int t = blockIdx.x * 4 + wave;
    if (t >= (N_NODES / 16)) return;   // 3125 tiles exactly

    const float* xr = X + (size_t)(t * 16 + ln) * DD;
    short8 a[4];
#pragma unroll
    for (int ks = 0; ks < 4; ++ks) {
        const float* p = xr + ks * 32 + g * 8;
        float4 t0 = *(const float4*)p;
        float4 t1 = *(const float4*)(p + 4);
        short8 v;
        v[0] = f2bf(t0.x); v[1] = f2bf(t0.y); v[2] = f2bf(t0.z); v[3] = f2bf(t0.w);
        v[4] = f2bf(t1.x); v[5] = f2bf(t1.y); v[6] = f2bf(t1.z); v[7] = f2bf(t1.w);
        a[ks] = v;
    }
#pragma unroll
    for (int nt = 0; nt < 8; ++nt) {
        f32x4 acc = {0.f, 0.f, 0.f, 0.f};
#pragma unroll
        for (int ks = 0; ks < 4; ++ks) {
            short8 b = *(const short8*)&Wl[(nt * 16 + ln) * 136 + ks * 32 + g * 8];
            acc = __builtin_amdgcn_mfma_f32_16x16x32_bf16(a[ks], b, acc, 0, 0, 0);
        }
        const int col = nt * 16 + ln;
        const float bb = bias[col];
#pragma unroll
        for (int r = 0; r < 4; ++r)
            Y[(size_t)(t * 16 + g * 4 + r) * DD + col] = f2bf(acc[r] + bb);
    }
}

// ---------------------------------------------------------------------------
// CSR construction: zero counts -> histogram -> 2-level scan -> scatter
// ---------------------------------------------------------------------------
__global__ __launch_bounds__(256) void k_zero_int(int* __restrict__ p, int n) {
    int i = blockIdx.x * 256 + threadIdx.x;
    if (i < n) p[i] = 0;
}

__global__ __launch_bounds__(256) void k_count(const int* __restrict__ EI,
                                               int* __restrict__ counts) {
    int e = blockIdx.x * 256 + threadIdx.x;
    if (e < N_EDGES) atomicAdd(&counts[EI[2 * e + 1]], 1);
}

__global__ __launch_bounds__(256) void k_scan1(const int* __restrict__ counts,
                                               int* __restrict__ scanned,
                                               int* __restrict__ bsum) {
    __shared__ int tmp[256];
    const int t = threadIdx.x;
    const int i = blockIdx.x * 256 + t;
    int v = (i < N_NODES) ? counts[i] : 0;
    tmp[t] = v;
    __syncthreads();
#pragma unroll
    for (int off = 1; off < 256; off <<= 1) {
        int x = (t >= off) ? tmp[t - off] : 0;
        __syncthreads();
        tmp[t] += x;
        __syncthreads();
    }
    if (i < N_NODES) scanned[i] = tmp[t] - v;   // exclusive
    if (t == 255) bsum[blockIdx.x] = tmp[255];
}

__global__ __launch_bounds__(256) void k_scan2(int* __restrict__ bsum, int nb) {
    __shared__ int tmp[256];
    const int t = threadIdx.x;
    int v = (t < nb) ? bsum[t] : 0;
    tmp[t] = v;
    __syncthreads();
#pragma unroll
    for (int off = 1; off < 256; off <<= 1) {
        int x = (t >= off) ? tmp[t - off] : 0;
        __syncthreads();
        tmp[t] += x;
        __syncthreads();
    }
    if (t < nb) bsum[t] = tmp[t] - v;           // exclusive
}

__global__ __launch_bounds__(256) void k_scan3(const int* __restrict__ scanned,
                                               const int* __restrict__ bsum,
                                               int* __restrict__ offsets,
                                               int* __restrict__ cursor) {
    int i = blockIdx.x * 256 + threadIdx.x;
    if (i < N_NODES) {
        int off = scanned[i] + bsum[blockIdx.x];
        offsets[i] = off;
        cursor[i] = off;
    }
    if (i == 0) offsets[N_NODES] = N_EDGES;
}

__global__ __launch_bounds__(256) void k_scatter(const int* __restrict__ EI,
                                                 int* __restrict__ cursor,
                                                 int2* __restrict__ sorted) {
    int e = blockIdx.x * 256 + threadIdx.x;
    if (e < N_EDGES) {
        int2 sd = *(const int2*)(EI + 2 * e);
        int pos = atomicAdd(&cursor[sd.y], 1);
        sorted[pos] = make_int2(e, sd.x);       // {edge id, src}
    }
}

// ---------------------------------------------------------------------------
// Aggregation: one wave per node. Fused rel-GEMM (MFMA over 16-edge chunks) +
// gather obj_lin[src]/[dst] (bf16) + per-edge ReLU + register segment-sum.
// No fp32 atomics.
// ---------------------------------------------------------------------------
__global__ __launch_bounds__(256) void k_aggr(const float* __restrict__ RV,
                                              const int2* __restrict__ sorted,
                                              const int* __restrict__ offs,
                                              const float* __restrict__ W,
                                              const float* __restrict__ bias,
                                              const short* __restrict__ OL,
                                              float* __restrict__ out) {
    __shared__ __align__(16) short Wl[128 * 136];
    for (int i = threadIdx.x; i < 128 * 128; i += 256) {
        int n = i >> 7, k = i & 127;
        Wl[n * 136 + k] = f2bf(W[i]);
    }
    __syncthreads();

    const int wave = threadIdx.x >> 6;
    const int lane = threadIdx.x & 63;
    const int g = lane >> 4, ln = lane & 15;
    const int nWaves = gridDim.x * 4;

    float brel[8];
#pragma unroll
    for (int nt = 0; nt < 8; ++nt) brel[nt] = bias[nt * 16 + ln];

    for (int v = blockIdx.x * 4 + wave; v < N_NODES; v += nWaves) {
        const int r0 = offs[v], r1 = offs[v + 1];

        float od[8];
#pragma unroll
        for (int nt = 0; nt < 8; ++nt)
            od[nt] = bf2f(OL[(size_t)v * DD + nt * 16 + ln]);

        float p[8] = {0.f, 0.f, 0.f, 0.f, 0.f, 0.f, 0.f, 0.f};

        for (int base = r0; base < r1; base += 16) {
            // A-fragment: row ln <- rel_vecs[edge at base+ln]
            int posl = base + ln;
            if (posl >= r1) posl = r1 - 1;      // clamp; masked in epilogue
            const int e_ln = sorted[posl].x;
            const float* xr = RV + (size_t)e_ln * DD;

            short8 a[4];
#pragma unroll
            for (int ks = 0; ks < 4; ++ks) {
                const float* pp = xr + ks * 32 + g * 8;
                float4 t0 = *(const float4*)pp;
                float4 t1 = *(const float4*)(pp + 4);
                short8 vv;
                vv[0] = f2bf(t0.x); vv[1] = f2bf(t0.y); vv[2] = f2bf(t0.z); vv[3] = f2bf(t0.w);
                vv[4] = f2bf(t1.x); vv[5] = f2bf(t1.y); vv[6] = f2bf(t1.z); vv[7] = f2bf(t1.w);
                a[ks] = vv;
            }

            f32x4 acc[8];
#pragma unroll
            for (int nt = 0; nt < 8; ++nt) {
                acc[nt] = (f32x4){0.f, 0.f, 0.f, 0.f};
#pragma unroll
                for (int ks = 0; ks < 4; ++ks) {
                    short8 b = *(const short8*)&Wl[(nt * 16 + ln) * 136 + ks * 32 + g * 8];
                    acc[nt] = __builtin_amdgcn_mfma_f32_16x16x32_bf16(a[ks], b, acc[nt], 0, 0, 0);
                }
            }

            // epilogue: lane (g,ln) owns rows g*4+r (col = nt*16+ln)
#pragma unroll
            for (int r = 0; r < 4; ++r) {
                const int pos = base + g * 4 + r;
                if (pos < r1) {
                    const int src = sorted[pos].y;
                    const short* ps = OL + (size_t)src * DD + ln;
#pragma unroll
                    for (int nt = 0; nt < 8; ++nt) {
                        float m = acc[nt][r] + brel[nt] + bf2f(ps[nt * 16]) + od[nt];
                        p[nt] += fmaxf(m, 0.f);
                    }
                }
            }
        }

        // reduce the 4 g-groups (lanes xor 16, xor 32) -> full column sums
#pragma unroll
        for (int nt = 0; nt < 8; ++nt) {
            p[nt] += __shfl_xor(p[nt], 16);
            p[nt] += __shfl_xor(p[nt], 32);
        }
        // store: group g writes cols nt=2g, 2g+1 (16 lanes x 64B contiguous)
#pragma unroll
        for (int nt = 0; nt < 8; ++nt) {
            if ((nt >> 1) == g)
                out[(size_t)v * DD + nt * 16 + ln] = fmaxf(p[nt], 0.f);
        }
    }
}

// ---------------------------------------------------------------------------
extern "C" void kernel_launch(void* const* d_in, const int* in_sizes, int n_in,
                              void* d_out, int out_size, void* d_ws, size_t ws_size,
                              hipStream_t stream) {
    const float* obj = (const float*)d_in[0];
    const float* rel = (const float*)d_in[1];
    const int*   ei  = (const int*)d_in[2];
    const float* Wo  = (const float*)d_in[3];
    const float* bo  = (const float*)d_in[4];
    const float* Wr  = (const float*)d_in[5];
    const float* br  = (const float*)d_in[6];
    float* out = (float*)d_out;

    // workspace layout (all 256B aligned)
    char* ws = (char*)d_ws;
    short* objlin  = (short*)ws;                               // 12,800,000 B
    int2*  sorted  = (int2*)(ws + 12800000);                   //  4,800,000 B
    int*   counts  = (int*)(ws + 17600000);                    //    200,000 B
    int*   scanned = (int*)(ws + 17800192);                    //    200,704 B (50176 ints)
    int*   offsets = (int*)(ws + 18000896);                    //    200,704 B (50001 ints)
    int*   cursor  = (int*)(ws + 18201600);                    //    200,000 B
    int*   bsum    = (int*)(ws + 18401792);                    //      1,024 B

    const int NB_E = (N_EDGES + 255) / 256;    // 2344
    const int NB_N = (N_NODES + 255) / 256;    // 196

    k_zero_int<<<NB_N, 256, 0, stream>>>(counts, N_NODES);
    k_objlin<<<(N_NODES / 16 + 3) / 4, 256, 0, stream>>>(obj, Wo, bo, objlin);
    k_count<<<NB_E, 256, 0, stream>>>(ei, counts);
    k_scan1<<<NB_N, 256, 0, stream>>>(counts, scanned, bsum);
    k_scan2<<<1, 256, 0, stream>>>(bsum, NB_N);
    k_scan3<<<NB_N, 256, 0, stream>>>(scanned, bsum, offsets, cursor);
    k_scatter<<<NB_E, 256, 0, stream>>>(ei, cursor, sorted);
    k_aggr<<<2048, 256, 0, stream>>>(rel, sorted, offsets, Wr, br, objlin, out);
}

// Round 3
// 270.178 us; speedup vs baseline: 1.3698x; 1.2378x over previous
//
#include <hip/hip_runtime.h>

#define N_NODES 50000
#define N_EDGES 600000
#define DD 128

typedef __attribute__((ext_vector_type(8))) short short8;
typedef __attribute__((ext_vector_type(4))) float f32x4;

__device__ __forceinline__ short f2bf(float f) {
    union { float f; unsigned u; } v; v.f = f;
    unsigned r = v.u + 0x7fffu + ((v.u >> 16) & 1u);
    return (short)(r >> 16);
}
__device__ __forceinline__ float bf2f(short s) {
    union { float f; unsigned u; } v; v.u = ((unsigned)(unsigned short)s) << 16;
    return v.f;
}
__device__ __forceinline__ float u2f(unsigned u) {
    union { float f; unsigned u; } v; v.u = u;
    return v.f;
}

// ---------------------------------------------------------------------------
// Streaming GEMM: Y[r][:] = X[r][:] @ W^T + bias  -> bf16. 16-row MFMA tiles,
// 4 waves/block, grid-stride over tiles.
// ---------------------------------------------------------------------------
__global__ __launch_bounds__(256) void k_lin(const float* __restrict__ X,
                                             const float* __restrict__ W,
                                             const float* __restrict__ bias,
                                             short* __restrict__ Y,
                                             int ntiles) {
    __shared__ __align__(16) short Wl[128 * 136];
    for (int i = threadIdx.x; i < 128 * 128; i += 256) {
        int n = i >> 7, k = i & 127;
        Wl[n * 136 + k] = f2bf(W[i]);
    }
    __syncthreads();

    const int wave = threadIdx.x >> 6;
    const int lane = threadIdx.x & 63;
    const int g = lane >> 4, ln = lane & 15;

    float bb[8];
#pragma unroll
    for (int nt = 0; nt < 8; ++nt) bb[nt] = bias[nt * 16 + ln];

    for (int t = blockIdx.x * 4 + wave; t < ntiles; t += gridDim.x * 4) {
        const float* xr = X + (size_t)(t * 16 + ln) * DD;
        short8 a[4];
#pragma unroll
        for (int ks = 0; ks < 4; ++ks) {
            const float* p = xr + ks * 32 + g * 8;
            float4 t0 = *(const float4*)p;
            float4 t1 = *(const float4*)(p + 4);
            short8 v;
            v[0] = f2bf(t0.x); v[1] = f2bf(t0.y); v[2] = f2bf(t0.z); v[3] = f2bf(t0.w);
            v[4] = f2bf(t1.x); v[5] = f2bf(t1.y); v[6] = f2bf(t1.z); v[7] = f2bf(t1.w);
            a[ks] = v;
        }
#pragma unroll
        for (int nt = 0; nt < 8; ++nt) {
            f32x4 acc = {0.f, 0.f, 0.f, 0.f};
#pragma unroll
            for (int ks = 0; ks < 4; ++ks) {
                short8 b = *(const short8*)&Wl[(nt * 16 + ln) * 136 + ks * 32 + g * 8];
                acc = __builtin_amdgcn_mfma_f32_16x16x32_bf16(a[ks], b, acc, 0, 0, 0);
            }
#pragma unroll
            for (int r = 0; r < 4; ++r)
                Y[(size_t)(t * 16 + g * 4 + r) * DD + nt * 16 + ln] = f2bf(acc[r] + bb[nt]);
        }
    }
}

// ---------------------------------------------------------------------------
// CSR construction: zero counts -> histogram -> 2-level scan -> scatter
// ---------------------------------------------------------------------------
__global__ __launch_bounds__(256) void k_zero_int(int* __restrict__ p, int n) {
    int i = blockIdx.x * 256 + threadIdx.x;
    if (i < n) p[i] = 0;
}

__global__ __launch_bounds__(256) void k_count(const int* __restrict__ EI,
                                               int* __restrict__ counts) {
    int e = blockIdx.x * 256 + threadIdx.x;
    if (e < N_EDGES) atomicAdd(&counts[EI[2 * e + 1]], 1);
}

__global__ __launch_bounds__(256) void k_scan1(const int* __restrict__ counts,
                                               int* __restrict__ scanned,
                                               int* __restrict__ bsum) {
    __shared__ int tmp[256];
    const int t = threadIdx.x;
    const int i = blockIdx.x * 256 + t;
    int v = (i < N_NODES) ? counts[i] : 0;
    tmp[t] = v;
    __syncthreads();
#pragma unroll
    for (int off = 1; off < 256; off <<= 1) {
        int x = (t >= off) ? tmp[t - off] : 0;
        __syncthreads();
        tmp[t] += x;
        __syncthreads();
    }
    if (i < N_NODES) scanned[i] = tmp[t] - v;
    if (t == 255) bsum[blockIdx.x] = tmp[255];
}

__global__ __launch_bounds__(256) void k_scan2(int* __restrict__ bsum, int nb) {
    __shared__ int tmp[256];
    const int t = threadIdx.x;
    int v = (t < nb) ? bsum[t] : 0;
    tmp[t] = v;
    __syncthreads();
#pragma unroll
    for (int off = 1; off < 256; off <<= 1) {
        int x = (t >= off) ? tmp[t - off] : 0;
        __syncthreads();
        tmp[t] += x;
        __syncthreads();
    }
    if (t < nb) bsum[t] = tmp[t] - v;
}

__global__ __launch_bounds__(256) void k_scan3(const int* __restrict__ scanned,
                                               const int* __restrict__ bsum,
                                               int* __restrict__ offsets,
                                               int* __restrict__ cursor) {
    int i = blockIdx.x * 256 + threadIdx.x;
    if (i < N_NODES) {
        int off = scanned[i] + bsum[blockIdx.x];
        offsets[i] = off;
        cursor[i] = off;
    }
    if (i == 0) offsets[N_NODES] = N_EDGES;
}

__global__ __launch_bounds__(256) void k_scatter(const int* __restrict__ EI,
                                                 int* __restrict__ cursor,
                                                 int2* __restrict__ sorted) {
    int e = blockIdx.x * 256 + threadIdx.x;
    if (e < N_EDGES) {
        int2 sd = *(const int2*)(EI + 2 * e);
        int pos = atomicAdd(&cursor[sd.y], 1);
        sorted[pos] = make_int2(e, sd.x);       // {edge id, src}
    }
}

// ---------------------------------------------------------------------------
// Gather-aggregate: one wave per node. Per edge: full 256B bf16 rows of
// RL[eid] and OL[src], 4B/lane (2 cols). fp32 accumulate, coalesced store.
// ---------------------------------------------------------------------------
__global__ __launch_bounds__(256) void k_gather(const short* __restrict__ RL,
                                                const short* __restrict__ OL,
                                                const int2* __restrict__ sorted,
                                                const int* __restrict__ offs,
                                                float* __restrict__ out) {
    const int wave = threadIdx.x >> 6;
    const int lane = threadIdx.x & 63;
    const int v = blockIdx.x * 4 + wave;
    if (v >= N_NODES) return;

    const int r0 = offs[v], r1 = offs[v + 1];
    const int deg = r1 - r0;

    const unsigned odu = *(const unsigned*)(OL + (size_t)v * DD + 2 * lane);
    const float od0 = u2f(odu << 16), od1 = u2f(odu & 0xffff0000u);

    float a0 = 0.f, a1 = 0.f;
    const int2* sp = sorted + r0;

    for (int base = 0; base < deg; base += 64) {
        const int nn = min(64, deg - base);
        int2 mp = make_int2(0, 0);
        if (lane < nn) mp = sp[base + lane];

        int e = 0;
        for (; e + 8 <= nn; e += 8) {
            unsigned rl[8], sl[8];
#pragma unroll
            for (int j = 0; j < 8; ++j) {
                const int eid = __shfl(mp.x, e + j);
                const int src = __shfl(mp.y, e + j);
                rl[j] = *(const unsigned*)(RL + (size_t)eid * DD + 2 * lane);
                sl[j] = *(const unsigned*)(OL + (size_t)src * DD + 2 * lane);
            }
#pragma unroll
            for (int j = 0; j < 8; ++j) {
                a0 += fmaxf(u2f(rl[j] << 16) + u2f(sl[j] << 16) + od0, 0.f);
                a1 += fmaxf(u2f(rl[j] & 0xffff0000u) + u2f(sl[j] & 0xffff0000u) + od1, 0.f);
            }
        }
        for (; e < nn; ++e) {
            const int eid = __shfl(mp.x, e);
            const int src = __shfl(mp.y, e);
            const unsigned rlu = *(const unsigned*)(RL + (size_t)eid * DD + 2 * lane);
            const unsigned slu = *(const unsigned*)(OL + (size_t)src * DD + 2 * lane);
            a0 += fmaxf(u2f(rlu << 16) + u2f(slu << 16) + od0, 0.f);
            a1 += fmaxf(u2f(rlu & 0xffff0000u) + u2f(slu & 0xffff0000u) + od1, 0.f);
        }
    }

    float2 o;
    o.x = fmaxf(a0, 0.f);
    o.y = fmaxf(a1, 0.f);
    *(float2*)(out + (size_t)v * DD + 2 * lane) = o;
}

// ---------------------------------------------------------------------------
// Fallback aggregation (round-2 style, used only if ws_size is too small):
// fused rel GEMM per node from raw fp32 rel_vecs.
// ---------------------------------------------------------------------------
__global__ __launch_bounds__(256) void k_aggr(const float* __restrict__ RV,
                                              const int2* __restrict__ sorted,
                                              const int* __restrict__ offs,
                                              const float* __restrict__ W,
                                              const float* __restrict__ bias,
                                              const short* __restrict__ OL,
                                              float* __restrict__ out) {
    __shared__ __align__(16) short Wl[128 * 136];
    for (int i = threadIdx.x; i < 128 * 128; i += 256) {
        int n = i >> 7, k = i & 127;
        Wl[n * 136 + k] = f2bf(W[i]);
    }
    __syncthreads();

    const int wave = threadIdx.x >> 6;
    const int lane = threadIdx.x & 63;
    const int g = lane >> 4, ln = lane & 15;
    const int nWaves = gridDim.x * 4;

    float brel[8];
#pragma unroll
    for (int nt = 0; nt < 8; ++nt) brel[nt] = bias[nt * 16 + ln];

    for (int v = blockIdx.x * 4 + wave; v < N_NODES; v += nWaves) {
        const int r0 = offs[v], r1 = offs[v + 1];
        float od[8];
#pragma unroll
        for (int nt = 0; nt < 8; ++nt)
            od[nt] = bf2f(OL[(size_t)v * DD + nt * 16 + ln]);
        float p[8] = {0.f, 0.f, 0.f, 0.f, 0.f, 0.f, 0.f, 0.f};

        for (int base = r0; base < r1; base += 16) {
            int posl = base + ln;
            if (posl >= r1) posl = r1 - 1;
            const int e_ln = sorted[posl].x;
            const float* xr = RV + (size_t)e_ln * DD;
            short8 a[4];
#pragma unroll
            for (int ks = 0; ks < 4; ++ks) {
                const float* pp = xr + ks * 32 + g * 8;
                float4 t0 = *(const float4*)pp;
                float4 t1 = *(const float4*)(pp + 4);
                short8 vv;
                vv[0] = f2bf(t0.x); vv[1] = f2bf(t0.y); vv[2] = f2bf(t0.z); vv[3] = f2bf(t0.w);
                vv[4] = f2bf(t1.x); vv[5] = f2bf(t1.y); vv[6] = f2bf(t1.z); vv[7] = f2bf(t1.w);
                a[ks] = vv;
            }
            f32x4 acc[8];
#pragma unroll
            for (int nt = 0; nt < 8; ++nt) {
                acc[nt] = (f32x4){0.f, 0.f, 0.f, 0.f};
#pragma unroll
                for (int ks = 0; ks < 4; ++ks) {
                    short8 b = *(const short8*)&Wl[(nt * 16 + ln) * 136 + ks * 32 + g * 8];
                    acc[nt] = __builtin_amdgcn_mfma_f32_16x16x32_bf16(a[ks], b, acc[nt], 0, 0, 0);
                }
            }
#pragma unroll
            for (int r = 0; r < 4; ++r) {
                const int pos = base + g * 4 + r;
                if (pos < r1) {
                    const int src = sorted[pos].y;
                    const short* ps = OL + (size_t)src * DD + ln;
#pragma unroll
                    for (int nt = 0; nt < 8; ++nt) {
                        float m = acc[nt][r] + brel[nt] + bf2f(ps[nt * 16]) + od[nt];
                        p[nt] += fmaxf(m, 0.f);
                    }
                }
            }
        }
#pragma unroll
        for (int nt = 0; nt < 8; ++nt) {
            p[nt] += __shfl_xor(p[nt], 16);
            p[nt] += __shfl_xor(p[nt], 32);
        }
#pragma unroll
        for (int nt = 0; nt < 8; ++nt) {
            if ((nt >> 1) == g)
                out[(size_t)v * DD + nt * 16 + ln] = fmaxf(p[nt], 0.f);
        }
    }
}

// ---------------------------------------------------------------------------
extern "C" void kernel_launch(void* const* d_in, const int* in_sizes, int n_in,
                              void* d_out, int out_size, void* d_ws, size_t ws_size,
                              hipStream_t stream) {
    const float* obj = (const float*)d_in[0];
    const float* rel = (const float*)d_in[1];
    const int*   ei  = (const int*)d_in[2];
    const float* Wo  = (const float*)d_in[3];
    const float* bo  = (const float*)d_in[4];
    const float* Wr  = (const float*)d_in[5];
    const float* br  = (const float*)d_in[6];
    float* out = (float*)d_out;

    const int NB_E = (N_EDGES + 255) / 256;    // 2344
    const int NB_N = (N_NODES + 255) / 256;    // 196

    const size_t RL_BYTES = (size_t)N_EDGES * DD * 2;      // 153,600,000
    const size_t FAST_NEED = 173000000;

    char* ws = (char*)d_ws;

    if (ws_size >= FAST_NEED) {
        short* RLb     = (short*)ws;
        short* OLb     = (short*)(ws + RL_BYTES);                    // 12.8 MB
        int2*  sorted  = (int2*)(ws + RL_BYTES + 12800000);          //  4.8 MB
        int*   counts  = (int*)(ws + RL_BYTES + 17600000);
        int*   scanned = (int*)(ws + RL_BYTES + 17800192);
        int*   offsets = (int*)(ws + RL_BYTES + 18000896);
        int*   cursor  = (int*)(ws + RL_BYTES + 18201600);
        int*   bsum    = (int*)(ws + RL_BYTES + 18401792);

        k_zero_int<<<NB_N, 256, 0, stream>>>(counts, N_NODES);
        k_lin<<<782, 256, 0, stream>>>(obj, Wo, bo, OLb, N_NODES / 16);
        k_lin<<<2048, 256, 0, stream>>>(rel, Wr, br, RLb, N_EDGES / 16);
        k_count<<<NB_E, 256, 0, stream>>>(ei, counts);
        k_scan1<<<NB_N, 256, 0, stream>>>(counts, scanned, bsum);
        k_scan2<<<1, 256, 0, stream>>>(bsum, NB_N);
        k_scan3<<<NB_N, 256, 0, stream>>>(scanned, bsum, offsets, cursor);
        k_scatter<<<NB_E, 256, 0, stream>>>(ei, cursor, sorted);
        k_gather<<<(N_NODES + 3) / 4, 256, 0, stream>>>(RLb, OLb, sorted, offsets, out);
    } else {
        short* OLb     = (short*)ws;                                 // 12.8 MB
        int2*  sorted  = (int2*)(ws + 12800000);
        int*   counts  = (int*)(ws + 17600000);
        int*   scanned = (int*)(ws + 17800192);
        int*   offsets = (int*)(ws + 18000896);
        int*   cursor  = (int*)(ws + 18201600);
        int*   bsum    = (int*)(ws + 18401792);

        k_zero_int<<<NB_N, 256, 0, stream>>>(counts, N_NODES);
        k_lin<<<782, 256, 0, stream>>>(obj, Wo, bo, OLb, N_NODES / 16);
        k_count<<<NB_E, 256, 0, stream>>>(ei, counts);
        k_scan1<<<NB_N, 256, 0, stream>>>(counts, scanned, bsum);
        k_scan2<<<1, 256, 0, stream>>>(bsum, NB_N);
        k_scan3<<<NB_N, 256, 0, stream>>>(scanned, bsum, offsets, cursor);
        k_scatter<<<NB_E, 256, 0, stream>>>(ei, cursor, sorted);
        k_aggr<<<2048, 256, 0, stream>>>(rel, sorted, offsets, Wr, br, OLb, out);
    }
}